// Round 4
// baseline (289.084 us; speedup 1.0000x reference)
//
#include <hip/hip_runtime.h>
#include <math.h>

#define HH 2048
#define WW 2048
#define NB 256
#define NROWS (11 * HH)      // 22528 total rows
#define GRID_ROWS 1024       // 22528 / 1024 = 22 rows per block, exact

// softmax-expectation accumulator: running max, sum(e), sum(e*x), sum(e*y)
struct Tup { float m, z, sx, sy; };

__device__ __forceinline__ void comb(Tup& a, const Tup& b) {
  float Mn = fmaxf(a.m, b.m);
  // (m==Mn)?1:expf guard avoids (-inf)-(-inf) = NaN when merging identities
  float w1 = (a.m == Mn) ? 1.0f : expf(a.m - Mn);
  float w2 = (b.m == Mn) ? 1.0f : expf(b.m - Mn);
  a.z  = a.z  * w1 + b.z  * w2;
  a.sx = a.sx * w1 + b.sx * w2;
  a.sy = a.sy * w1 + b.sy * w2;
  a.m  = Mn;
}

// Online-softmax reduce of one row (WW cols). All threads get the result.
// NOTE: arithmetic & reduction order must stay bit-identical across rounds —
// the downstream floor/ceil band logic sits on a numerical knife-edge.
__device__ Tup row_reduce(const float* __restrict__ rowp) {
  const int tid = threadIdx.x;
  const float4* r4 = (const float4*)rowp;
  float m = -INFINITY, z = 0.0f, sx = 0.0f;
#pragma unroll
  for (int p = 0; p < WW / (4 * NB); ++p) {
    int i4 = tid + NB * p;
    float4 v = r4[i4];
    float vv[4] = {v.x, v.y, v.z, v.w};
    float c0 = (float)(i4 * 4);
#pragma unroll
    for (int k = 0; k < 4; ++k) {
      float x = vv[k] * 100.0f;   // BETA, matches reference f32 multiply
      if (x > m) {
        float sc = expf(m - x);   // first iter: expf(-inf) = 0
        z  = z  * sc + 1.0f;
        sx = sx * sc + (c0 + (float)k);
        m = x;
      } else {
        float w = expf(x - m);
        z  += w;
        sx += w * (c0 + (float)k);
      }
    }
  }
  __shared__ float sm_[NB], sz_[NB], ss_[NB];
  __syncthreads();              // WAR guard for repeated calls
  sm_[tid] = m; sz_[tid] = z; ss_[tid] = sx;
  __syncthreads();
  for (int off = NB / 2; off > 0; off >>= 1) {
    if (tid < off) {
      Tup a = {sm_[tid], sz_[tid], ss_[tid], 0.0f};
      Tup b = {sm_[tid + off], sz_[tid + off], ss_[tid + off], 0.0f};
      comb(a, b);
      sm_[tid] = a.m; sz_[tid] = a.z; ss_[tid] = a.sx;
    }
    __syncthreads();
  }
  Tup t = {sm_[0], sz_[0], ss_[0], 0.0f};
  return t;
}

__device__ Tup block_reduce4(Tup t) {
  __shared__ float am[NB], az[NB], axx[NB], ayy[NB];
  const int tid = threadIdx.x;
  __syncthreads();              // WAR guard for repeated calls
  am[tid] = t.m; az[tid] = t.z; axx[tid] = t.sx; ayy[tid] = t.sy;
  __syncthreads();
  for (int off = NB / 2; off > 0; off >>= 1) {
    if (tid < off) {
      Tup a = {am[tid], az[tid], axx[tid], ayy[tid]};
      Tup b = {am[tid + off], az[tid + off], axx[tid + off], ayy[tid + off]};
      comb(a, b);
      am[tid] = a.m; az[tid] = a.z; axx[tid] = a.sx; ayy[tid] = a.sy;
    }
    __syncthreads();
  }
  Tup r = {am[0], az[0], axx[0], ayy[0]};
  return r;
}

// Merge per-row partials arr[r], r in [s,e]; sy weight = r. All threads get result.
__device__ Tup merge_rows(const float4* arr, int s, int e) {
  Tup acc = {-INFINITY, 0.0f, 0.0f, 0.0f};
  for (int r = s + (int)threadIdx.x; r <= e; r += NB) {
    float4 p = arr[r];
    Tup q = {p.x, p.y, p.z, p.y * (float)r};
    comb(acc, q);
  }
  return block_reduce4(acc);
}

// Add analytic out-of-band complement (masked elements are exactly 0) and divide.
__device__ void finalize(Tup acc, int s, int e, bool valid, float& ax, float& ay) {
  float M = acc.m, Z = acc.z, SX = acc.sx, SY = acc.sy;
  int nin = valid ? (e - s + 1) : 0;
  int nout = HH - nin;
  if (nout > 0) {
    float M2 = fmaxf(M, 0.0f);
    float wi = (M == M2) ? 1.0f : expf(M - M2);   // M=-inf -> 0
    float wo = (M2 == 0.0f) ? 1.0f : expf(-M2);   // underflows to 0 for typical M
    Z *= wi; SX *= wi; SY *= wi;
    float nout_e = (float)nout * (float)WW;                                 // exact
    float sox = (float)nout * 2096128.0f;                                   // nout*W(W-1)/2
    float sinr = valid ? (float)(((long)(s + e) * (e - s + 1)) / 2) : 0.0f; // exact
    float soy = (2096128.0f - sinr) * 2048.0f;                              // exact
    Z  += wo * nout_e;
    SX += wo * sox;
    SY += wo * soy;
  }
  ax = SX / Z; ay = SY / Z;
}

// ws layout: [0..31] header (unused), F = 11*2048 x float4 per-row partials.

// Fat blocks: 1024 blocks x 22 rows each — amortizes the ~11.5 ns/block
// workgroup dispatch cost that made 22528 one-row blocks take 259 us (R3).
// Per-row math is bit-identical to the one-block-per-row version.
__global__ __launch_bounds__(NB) void k_rows_all(const float* __restrict__ heat,
                                                 float* ws) {
  float4* F = (float4*)(ws + 32);
  for (int b = blockIdx.x; b < NROWS; b += GRID_ROWS) {
    Tup t = row_reduce(heat + (size_t)b * WW);
    if (threadIdx.x == 0) F[b] = make_float4(t.m, t.z, t.sx, 0.0f);
  }
}

// Single block walks the whole sequential chain over precomputed partials.
__global__ __launch_bounds__(NB) void k_chain(float* ws, float* __restrict__ out) {
  const float4* F = (const float4*)(ws + 32);
  float st[22];
  float ax, ay;

  Tup a9 = merge_rows(F + 9 * HH, 0, HH - 1);
  finalize(a9, 0, HH - 1, true, ax, ay);  st[18] = ax; st[19] = ay;   // out[9]
  Tup a10 = merge_rows(F + 10 * HH, 0, HH - 1);
  finalize(a10, 0, HH - 1, true, ax, ay); st[20] = ax; st[21] = ay;   // out[10]

  float dis = st[21] - st[19], dsum = 0.0f, dnum = 0.0f;

  for (int i = 8; i >= 0; --i) {
    float y1 = st[2 * (i + 1) + 1];
    float y2 = st[2 * (i + 2) + 1];
    float last_y = floorf(y1);
    float tmp = ceilf(y2 - y1);
    bool cond = fabsf(tmp - dis) > 0.35f * dis;
    if (cond) { dsum += tmp; dnum += 1.0f; dis = dsum / fmaxf(dnum, 1.0f); }
    float start_raw = last_y - 1.8f * dis;
    float end_f   = rintf(start_raw + 1.8f * dis);  // jnp.round = rint (half-to-even)
    float start_f = rintf(start_raw);
    int s = (int)fmaxf(start_f, 0.0f);
    int e = (int)fminf(end_f, (float)(HH - 1));
    bool valid = (s <= e) && (end_f >= 0.0f) && (start_f <= (float)(HH - 1));
    Tup acc = {-INFINITY, 0.0f, 0.0f, 0.0f};
    if (valid) acc = merge_rows(F + (size_t)i * HH, s, e);  // block-uniform branch
    finalize(acc, s, e, valid, ax, ay);
    st[2 * i] = ax; st[2 * i + 1] = ay;
  }

  if (threadIdx.x < 22) out[threadIdx.x] = st[threadIdx.x];
}

extern "C" void kernel_launch(void* const* d_in, const int* in_sizes, int n_in,
                              void* d_out, int out_size, void* d_ws, size_t ws_size,
                              hipStream_t stream) {
  const float* heat = (const float*)d_in[0];
  float* out = (float*)d_out;
  float* ws = (float*)d_ws;
  hipLaunchKernelGGL(k_rows_all, dim3(GRID_ROWS), dim3(NB), 0, stream, heat, ws);
  hipLaunchKernelGGL(k_chain, dim3(1), dim3(NB), 0, stream, ws, out);
}

// Round 5
// 243.480 us; speedup vs baseline: 1.1873x; 1.1873x over previous
//
#include <hip/hip_runtime.h>
#include <math.h>

#define HH 2048
#define WW 2048
#define NB 256
#define STAGE_GRID 512

// ---------- wave / block reduction primitives (no LDS trees) ----------

__device__ __forceinline__ float wave_fmax(float v) {
#pragma unroll
  for (int m = 1; m < 64; m <<= 1) v = fmaxf(v, __shfl_xor(v, m, 64));
  return v;
}
__device__ __forceinline__ float wave_fsum(float v) {
#pragma unroll
  for (int m = 1; m < 64; m <<= 1) v += __shfl_xor(v, m, 64);
  return v;
}

// Block-wide max over 256 threads (4 waves). 2 barriers.
__device__ float block_fmax(float v) {
  __shared__ float s[4];
  v = wave_fmax(v);
  __syncthreads();                       // WAR guard across calls
  if ((threadIdx.x & 63) == 0) s[threadIdx.x >> 6] = v;
  __syncthreads();
  return fmaxf(fmaxf(s[0], s[1]), fmaxf(s[2], s[3]));
}

// Block-wide sum of three values. 2 barriers.
__device__ void block_fsum3(float& a, float& b, float& c) {
  __shared__ float sa[4], sb[4], sc[4];
  a = wave_fsum(a); b = wave_fsum(b); c = wave_fsum(c);
  __syncthreads();                       // WAR guard across calls
  if ((threadIdx.x & 63) == 0) {
    int w = threadIdx.x >> 6;
    sa[w] = a; sb[w] = b; sc[w] = c;
  }
  __syncthreads();
  a = (sa[0] + sa[1]) + (sa[2] + sa[3]);
  b = (sb[0] + sb[1]) + (sb[2] + sb[3]);
  c = (sc[0] + sc[1]) + (sc[2] + sc[3]);
}

// ---------- per-row softmax partial, computed by ONE wave, no barriers ----------
// Returns (M, z, sx) with z = sum(exp(100*v - M)), sx = sum(exp * col).
__device__ float4 wave_row_partial(const float* __restrict__ rowp) {
  const int lane = threadIdx.x & 63;
  const float4* r4 = (const float4*)rowp;
  float d[32];
  float m = -INFINITY;
#pragma unroll
  for (int p = 0; p < 8; ++p) {
    float4 v = r4[lane + 64 * p];
    d[4 * p + 0] = v.x * 100.0f;  // BETA
    d[4 * p + 1] = v.y * 100.0f;
    d[4 * p + 2] = v.z * 100.0f;
    d[4 * p + 3] = v.w * 100.0f;
    m = fmaxf(m, fmaxf(fmaxf(d[4 * p], d[4 * p + 1]), fmaxf(d[4 * p + 2], d[4 * p + 3])));
  }
  float M = wave_fmax(m);
  float z = 0.0f, sx = 0.0f;
#pragma unroll
  for (int p = 0; p < 8; ++p) {
    float c0 = (float)(4 * (lane + 64 * p));
#pragma unroll
    for (int k = 0; k < 4; ++k) {
      float e = expf(d[4 * p + k] - M);
      z += e;
      sx += e * (c0 + (float)k);
    }
  }
  z = wave_fsum(z);
  sx = wave_fsum(sx);
  return make_float4(M, z, sx, 0.0f);
}

// Merge per-row partials arr[r], r in [s,e] (sy weight = r). Block-wide, broadcast.
__device__ void merge_partials(const float4* __restrict__ arr, int s, int e,
                               float& M, float& Z, float& SX, float& SY) {
  float m = -INFINITY;
  for (int r = s + (int)threadIdx.x; r <= e; r += NB) m = fmaxf(m, arr[r].x);
  M = block_fmax(m);
  float z = 0.0f, sx = 0.0f, sy = 0.0f;
  for (int r = s + (int)threadIdx.x; r <= e; r += NB) {
    float4 p = arr[r];                   // L1/L2-hot second read
    float w = expf(p.x - M);
    z  += w * p.y;
    sx += w * p.z;
    sy += w * p.y * (float)r;
  }
  block_fsum3(z, sx, sy);
  Z = z; SX = sx; SY = sy;
}

// Analytic out-of-band complement (masked elements are exactly 0), then divide.
__device__ void finalize2(float M, float Z, float SX, float SY, int s, int e,
                          bool valid, float& ax, float& ay) {
  int nin = valid ? (e - s + 1) : 0;
  int nout = HH - nin;
  if (nout > 0) {
    float M2 = fmaxf(M, 0.0f);
    float wi = (M == M2) ? 1.0f : expf(M - M2);   // M=-inf -> 0
    float wo = (M2 == 0.0f) ? 1.0f : expf(-M2);   // underflows to 0 for typical M
    Z *= wi; SX *= wi; SY *= wi;
    float nout_e = (float)nout * (float)WW;                                  // exact
    float sox = (float)nout * 2096128.0f;                                    // nout*W(W-1)/2
    float sinr = valid ? (float)(((long)(s + e) * (e - s + 1)) / 2) : 0.0f;  // exact
    float soy = (2096128.0f - sinr) * 2048.0f;                               // exact
    Z  += wo * nout_e;
    SX += wo * sox;
    SY += wo * soy;
  }
  ax = SX / Z;
  ay = SY / Z;
}

// ---------- workspace layout (floats) ----------
// state slots: slot i at ws + 32*i, i in 0..8; each 28 floats:
//   [0..21] out, [22] dis, [23] dsum, [24] dnum, [25] band_s, [26] band_e, [27] valid
// F  at ws+512: 4096 x float4 (ch9 rows 0..2047, ch10 rows 2048..4095)
// B0 at F+4096: 2048 x float4; B1 at B0+2048 (ping-pong band partials, abs-row idx)

// Kernel A: per-wave row partials for channels 9,10. No barriers at all.
__global__ __launch_bounds__(NB) void k_rows910(const float* __restrict__ heat,
                                                float* ws) {
  float4* F = (float4*)(ws + 512);
  int gw = blockIdx.x * 4 + (threadIdx.x >> 6);       // 0..4095
  int ch = 9 + (gw >> 11);
  int r = gw & (HH - 1);
  float4 t = wave_row_partial(heat + ((size_t)ch * HH + r) * WW);
  if ((threadIdx.x & 63) == 0) F[gw] = t;
}

// Stage kernel. i=8: seed from F. i in [0,8): merge prev band. i=-1: final+output.
// Reads state slot i+1, writes state slot i (no same-slot read/write race).
__global__ __launch_bounds__(NB) void k_stage(const float* __restrict__ heat,
                                              float* ws, float* __restrict__ out,
                                              int i) {
  float4* F  = (float4*)(ws + 512);
  float4* B0 = F + 4096;
  float4* B1 = B0 + HH;

  float st[28];
  if (i == 8) {
    for (int k = 0; k < 28; ++k) st[k] = 0.0f;
    float M, Z, SX, SY, ax, ay;
    merge_partials(F, 0, HH - 1, M, Z, SX, SY);
    finalize2(M, Z, SX, SY, 0, HH - 1, true, ax, ay);
    st[18] = ax; st[19] = ay;                                   // out[9]
    merge_partials(F + HH, 0, HH - 1, M, Z, SX, SY);
    finalize2(M, Z, SX, SY, 0, HH - 1, true, ax, ay);
    st[20] = ax; st[21] = ay;                                   // out[10]
    st[22] = st[21] - st[19];                                   // dis0
    st[23] = 0.0f; st[24] = 0.0f;
  } else {
    const float* prev = ws + 32 * (i + 1);
    for (int k = 0; k < 28; ++k) st[k] = prev[k];
    const int j = i + 1;                                        // channel to finish
    const float4* Bprev = (j & 1) ? B1 : B0;
    int s = (int)st[25], e = (int)st[26];
    bool valid = (st[27] != 0.0f);                              // block-uniform
    float M = -INFINITY, Z = 0.0f, SX = 0.0f, SY = 0.0f, ax, ay;
    if (valid) merge_partials(Bprev, s, e, M, Z, SX, SY);
    finalize2(M, Z, SX, SY, s, e, valid, ax, ay);
    st[2 * j] = ax; st[2 * j + 1] = ay;
  }

  if (i >= 0) {
    // Band + dis-state update (all threads compute identically)
    float y1 = st[2 * (i + 1) + 1];
    float y2 = st[2 * (i + 2) + 1];
    float dis = st[22], dsum = st[23], dnum = st[24];
    float last_y = floorf(y1);
    float tmp = ceilf(y2 - y1);
    bool cond = fabsf(tmp - dis) > 0.35f * dis;
    if (cond) { dsum += tmp; dnum += 1.0f; dis = dsum / fmaxf(dnum, 1.0f); }
    float start_raw = last_y - 1.8f * dis;
    float end_f   = rintf(start_raw + 1.8f * dis);   // jnp.round = rint
    float start_f = rintf(start_raw);
    int s2 = (int)fmaxf(start_f, 0.0f);
    int e2 = (int)fminf(end_f, (float)(HH - 1));
    bool bvalid = (s2 <= e2) && (end_f >= 0.0f) && (start_f <= (float)(HH - 1));
    st[22] = dis; st[23] = dsum; st[24] = dnum;
    st[25] = (float)s2; st[26] = (float)e2; st[27] = bvalid ? 1.0f : 0.0f;

    float4* Bcur = (i & 1) ? B1 : B0;
    if (bvalid) {
      const int wid = (int)(blockIdx.x * 4) + (threadIdx.x >> 6);
      for (int r = s2 + wid; r <= e2; r += (int)gridDim.x * 4) {
        float4 t = wave_row_partial(heat + ((size_t)i * HH + r) * WW);
        if ((threadIdx.x & 63) == 0) Bcur[r] = t;
      }
    }
    if (blockIdx.x == 0 && threadIdx.x == 0) {
      float* slot = ws + 32 * i;
      for (int k = 0; k < 28; ++k) slot[k] = st[k];
    }
  } else {
    if (blockIdx.x == 0 && threadIdx.x < 22) out[threadIdx.x] = st[threadIdx.x];
  }
}

extern "C" void kernel_launch(void* const* d_in, const int* in_sizes, int n_in,
                              void* d_out, int out_size, void* d_ws, size_t ws_size,
                              hipStream_t stream) {
  const float* heat = (const float*)d_in[0];
  float* out = (float*)d_out;
  float* ws = (float*)d_ws;
  hipLaunchKernelGGL(k_rows910, dim3(1024), dim3(NB), 0, stream, heat, ws);
  for (int i = 8; i >= 0; --i) {
    hipLaunchKernelGGL(k_stage, dim3(STAGE_GRID), dim3(NB), 0, stream, heat, ws, out, i);
  }
  hipLaunchKernelGGL(k_stage, dim3(1), dim3(NB), 0, stream, heat, ws, out, -1);
}